// Round 3
// baseline (208.584 us; speedup 1.0000x reference)
//
#include <hip/hip_runtime.h>
#include <stdint.h>

// SAUCD simp_wt scoring: score[b,m] = clip( sum_l |w|[bin(lmbd[b,m,l+1])] * N[b,m,l] * areas[b,m,l], 0, 2 )
// B=8, M=16, L=131072 -> 128 rows of 131072 elements.
//
// R2: latency-bound fix via global_load_lds DMA staging (no dest regs -> compiler
// can't collapse the pipeline) + counted s_waitcnt vmcnt(6), double-buffered LDS,
// wave-local staging so the main loop needs no barriers.

#define TPB 512              // 8 waves
#define TILE 2048            // elements per tile
#define TILES_PER_BLOCK 16   // block covers 32768 elems = 1/4 row
#define NBLOCKS 512          // 4 blocks per row * 128 rows
#define ROW_L 131072

__device__ __forceinline__ void gload16(const float* g, float* l) {
    __builtin_amdgcn_global_load_lds((const __attribute__((address_space(1))) void*)g,
                                     (__attribute__((address_space(3))) void*)l, 16, 0, 0);
}
__device__ __forceinline__ void gload4(const float* g, float* l) {
    __builtin_amdgcn_global_load_lds((const __attribute__((address_space(1))) void*)g,
                                     (__attribute__((address_space(3))) void*)l, 4, 0, 0);
}

__device__ __forceinline__ int wbin(float l) {
    // clamp(floor((log(max(l,1e-8)) + 6.0) / 0.105), 0, 63)
    const float logl = __logf(fmaxf(l, 1e-8f));
    const float t = (logl + 6.0f) * 9.52380952380952381f;   // 1/0.105
    return (int)fminf(fmaxf(t, 0.0f), 63.0f);               // clamp-then-trunc == floor-then-clamp
}

__global__ __launch_bounds__(TPB) void saucd_reduce_kernel(
    const float* __restrict__ weight,      // [64]
    const float* __restrict__ narr,        // [128, 131072]
    const float* __restrict__ lmbd,        // [128, 131073]
    const float* __restrict__ areas,       // [128, 131072]
    float* __restrict__ out)               // [128], pre-zeroed
{
    __shared__ float bufN[2][TILE];
    __shared__ float bufA[2][TILE];
    __shared__ float bufL[2][TILE];
    __shared__ float w_abs[64];
    __shared__ float wave_sum[TPB / 64];

    const int tid  = threadIdx.x;
    const int lane = tid & 63;
    const int wbase = (tid >> 6) * 256;    // wave-local 256-elem slice of each tile

    if (tid < 64) w_abs[tid] = fabsf(weight[tid]);
    __syncthreads();                       // w_abs visible; drains vmcnt BEFORE any DMA issued

    const int b = blockIdx.x;
    const int row = b >> 2;
    const size_t base = (size_t)row * ROW_L + (size_t)(b & 3) * (TILE * TILES_PER_BLOCK);
    const float* nrow = narr  + base;
    const float* arow = areas + base;
    const float* lrow = lmbd  + (size_t)row * (ROW_L + 1)
                              + (size_t)(b & 3) * (TILE * TILES_PER_BLOCK) + 1;  // +1 shift

    // Stage one tile into buffer `which`. EXACTLY 6 VMEM instrs per wave per call.
    // All destinations are wave-local: wave w stages LDS [256w, 256w+256) of each array,
    // and compute reads only [4*tid, 4*tid+4) ⊂ that range -> no cross-wave deps, no barriers.
    auto stage = [&](int tk, int which) {
        const size_t off = (size_t)tk * TILE;
        gload16(nrow + off + (size_t)tid * 4, &bufN[which][tid * 4]);   // 1KB/wave
        gload16(arow + off + (size_t)tid * 4, &bufA[which][tid * 4]);   // 1KB/wave
#pragma unroll
        for (int k = 0; k < 4; ++k) {
            const int j = wbase + k * 64 + lane;   // wave-local, lane-linear (size=4 dest rule)
            gload4(lrow + off + j, &bufL[which][j]);                    // 256B/wave each
        }
    };

    stage(0, 0);

    float acc0 = 0.0f, acc1 = 0.0f, acc2 = 0.0f, acc3 = 0.0f;

#pragma unroll 1
    for (int t = 0; t < TILES_PER_BLOCK; ++t) {
        const int cur = t & 1;
        if (t + 1 < TILES_PER_BLOCK) {
            stage(t + 1, cur ^ 1);                         // 6 new DMAs in flight
            asm volatile("s_waitcnt vmcnt(6)" ::: "memory");  // tile t's 6 DMAs complete
        } else {
            asm volatile("s_waitcnt vmcnt(0)" ::: "memory");
        }
        const float4 lv = *(const float4*)&bufL[cur][tid * 4];
        const float4 nv = *(const float4*)&bufN[cur][tid * 4];
        const float4 av = *(const float4*)&bufA[cur][tid * 4];
        acc0 = fmaf(w_abs[wbin(lv.x)] * nv.x, av.x, acc0);
        acc1 = fmaf(w_abs[wbin(lv.y)] * nv.y, av.y, acc1);
        acc2 = fmaf(w_abs[wbin(lv.z)] * nv.z, av.z, acc2);
        acc3 = fmaf(w_abs[wbin(lv.w)] * nv.w, av.w, acc3);
    }

    float acc = (acc0 + acc1) + (acc2 + acc3);

    // wave (64-lane) butterfly reduce
#pragma unroll
    for (int off = 32; off > 0; off >>= 1)
        acc += __shfl_down(acc, off, 64);

    __syncthreads();                        // safe here: vmcnt already 0
    if (lane == 0) wave_sum[tid >> 6] = acc;
    __syncthreads();
    if (tid == 0) {
        float s = 0.0f;
#pragma unroll
        for (int w = 0; w < TPB / 64; ++w) s += wave_sum[w];
        atomicAdd(&out[row], s);            // 4 atomics/row
    }
}

__global__ void saucd_finalize_kernel(float* __restrict__ out, int n) {
    const int i = threadIdx.x + blockIdx.x * blockDim.x;
    if (i < n) out[i] = fminf(fmaxf(out[i], 0.0f), 2.0f);
}

extern "C" void kernel_launch(void* const* d_in, const int* in_sizes, int n_in,
                              void* d_out, int out_size, void* d_ws, size_t ws_size,
                              hipStream_t stream) {
    const float* weight = (const float*)d_in[0];   // [64]
    const float* narr   = (const float*)d_in[1];   // [8,16,131072]
    const float* lmbd   = (const float*)d_in[2];   // [8,16,131073]
    const float* areas  = (const float*)d_in[3];   // [8,16,131072]
    float* out = (float*)d_out;                    // [128] f32

    // d_out is poisoned 0xAA before every call — zero it for the atomic accumulate.
    hipMemsetAsync(out, 0, (size_t)out_size * sizeof(float), stream);

    saucd_reduce_kernel<<<NBLOCKS, TPB, 0, stream>>>(weight, narr, lmbd, areas, out);
    saucd_finalize_kernel<<<1, 128, 0, stream>>>(out, out_size);
}